// Round 17
// baseline (428.998 us; speedup 1.0000x reference)
//
#include <hip/hip_runtime.h>

#define N_NODES 100000
#define G_NODES 50000
#define N_EDGES 800000
#define H 64
#define F_IN 32
#define MAX_DEG 20
#define NUM_GRAPHS 128
#define LN_EPS 1e-5f
#define POOL_BLOCKS 256
#define MAX_TILES 1600

// Binned CSR build: 512 bins over the 4*N key space, FIXED 8192-entry
// capacity per bin (mean 6250, sigma~79 -> +24 sigma, unreachable).
#define NBINS 512
#define BPB 782            // keys per bin: 782*512 = 400384 >= 400000
#define BINCAP_LOG 13      // 8192 entries per bin
#define CHUNK 6250         // edges per build block: 6250*512 = 3.2M
#define MKEYS (4 * N_NODES)
#define MEDGES (4 * N_EDGES)

typedef __attribute__((ext_vector_type(8))) short short8;
typedef __attribute__((ext_vector_type(4))) float float4v;

// bf16 helpers (RNE), no header dependency
static __device__ __forceinline__ unsigned short f2b(float f) {
  unsigned u = __float_as_uint(f);
  return (unsigned short)((u + 0x7fffu + ((u >> 16) & 1u)) >> 16);
}
static __device__ __forceinline__ float b2f(unsigned short b) {
  return __uint_as_float(((unsigned)b) << 16);
}

// ---------------- weight preconvert + cursor/bcnt/done init (runs FIRST) ----
__global__ __launch_bounds__(256) void wconv_kernel(
    const float* __restrict__ wl, const float* __restrict__ wr,
    const float* __restrict__ ew, unsigned short* __restrict__ wbt,
    unsigned short* __restrict__ ewbt, int* __restrict__ bincur,
    int* __restrict__ bcnt, int* __restrict__ done) {
  int i = blockIdx.x * 256 + threadIdx.x;
  if (blockIdx.x == 0) {
    for (int k = threadIdx.x; k < NBINS; k += 256) bincur[k] = k << BINCAP_LOG;
    if (threadIdx.x < 84) bcnt[threadIdx.x] = 0;
    if (threadIdx.x == 128) *done = 0;
  }
  if (i < 84 * 64 * 128) {
    int k = i & 127;
    int ch = (i >> 7) & 63;
    int jb = i >> 13;
    float v = (k < 64) ? wl[jb * 4096 + k * 64 + ch]
                       : wr[jb * 4096 + (k - 64) * 64 + ch];
    wbt[i] = f2b(v);
  } else if (i < 84 * 64 * 128 + H * F_IN) {
    int ii = i - 84 * 64 * 128;
    int c = ii >> 5, f = ii & 31;
    ewbt[ii] = f2b(ew[f * H + c]);
  }
}

// ---------------- MFMA embedding + pooled zero-init -------------------------
__global__ __launch_bounds__(256) void emb_kernel(
    const float* __restrict__ x, const unsigned short* __restrict__ ewbt,
    const float* __restrict__ eb, float* __restrict__ h0,
    unsigned short* __restrict__ ab, float* __restrict__ pooled) {
  int tid = threadIdx.x;
  if (blockIdx.x == 0) {
    for (int i = tid; i < NUM_GRAPHS * H; i += 256) pooled[i] = 0.f;
  }
  int base = blockIdx.x * 64;
  int nIn = min(64, N_NODES - base);
  int qw = tid >> 6, lane = tid & 63;
  __shared__ unsigned short aL[64 * 40];  // stride 40 breaks pow2 banks
  __shared__ float outF[64 * 68];

  {
    int node = tid >> 2, chb = (tid & 3) * 8;
    unsigned short v8[8];
    if (node < nIn) {
      const float* xr = x + ((size_t)(base + node)) * F_IN + chb;
      float4 f0 = *(const float4*)(xr);
      float4 f1 = *(const float4*)(xr + 4);
      v8[0] = f2b(f0.x); v8[1] = f2b(f0.y); v8[2] = f2b(f0.z); v8[3] = f2b(f0.w);
      v8[4] = f2b(f1.x); v8[5] = f2b(f1.y); v8[6] = f2b(f1.z); v8[7] = f2b(f1.w);
    } else {
#pragma unroll
      for (int i = 0; i < 8; ++i) v8[i] = 0;
    }
    *(short8*)&aL[(tid >> 2) * 40 + chb] = *(short8*)v8;
  }
  // no __syncthreads: wave qw staged exactly rows [qw*16, qw*16+16)

  int m = lane & 15, quad = lane >> 4;
  short8 a = *(const short8*)&aL[(qw * 16 + m) * 40 + quad * 8];
  float4v acc[4];
#pragma unroll
  for (int t = 0; t < 4; ++t) {
    float bv = eb[t * 16 + m];
    acc[t] = (float4v){bv, bv, bv, bv};
  }
#pragma unroll
  for (int t = 0; t < 4; ++t) {
    short8 bf = *(const short8*)&ewbt[(t * 16 + m) * F_IN + quad * 8];
    acc[t] = __builtin_amdgcn_mfma_f32_16x16x32_bf16(a, bf, acc[t], 0, 0, 0);
  }
#pragma unroll
  for (int t = 0; t < 4; ++t)
#pragma unroll
    for (int r = 0; r < 4; ++r)
      outF[(qw * 16 + quad * 4 + r) * 68 + t * 16 + m] = acc[t][r];
  for (int r = qw * 16; r < qw * 16 + 16; ++r) {
    if (r < nIn) {
      int node = base + r;
      float v = outF[r * 68 + lane];
      if (node < G_NODES) h0[node * H + lane] = v;
      ab[node * 128 + 64 + lane] = f2b(v);
    }
  }
}

// ---------------- single-pass binning, 1024 threads -------------------------
// R16: 256-thread version was 44.6us at 16.9% occupancy (512 blocks = 2/CU =
// 8 waves/CU) — latency-bound on LDS-atomic chains. 1024 threads -> 32
// waves/CU cap, same per-block work.
__global__ __launch_bounds__(1024) void p3_binscatter(
    const int* __restrict__ e0, const int* __restrict__ e1,
    const int* __restrict__ e2, const int* __restrict__ e3,
    int* __restrict__ bincur, unsigned* __restrict__ binned) {
  __shared__ int hist[NBINS];
  __shared__ int cur[NBINS];
  int t = threadIdx.x, b = blockIdx.x;
  for (int i = t; i < NBINS; i += 1024) hist[i] = 0;
  __syncthreads();
  int j = b >> 7;
  const int* ei = (j == 0) ? e0 : (j == 1) ? e1 : (j == 2) ? e2 : e3;
  int ebase = (b & 127) * CHUNK;
  for (int i = t; i < CHUNK; i += 1024) {
    int dst = ei[N_EDGES + ebase + i];
    atomicAdd(&hist[(j * N_NODES + dst) / BPB], 1);
  }
  __syncthreads();
  for (int i = t; i < NBINS; i += 1024) {
    int c = hist[i];
    cur[i] = c ? atomicAdd(&bincur[i], c) : 0;
  }
  __syncthreads();
  for (int i = t; i < CHUNK; i += 1024) {
    int src = ei[ebase + i];
    int dst = ei[N_EDGES + ebase + i];
    int key = j * N_NODES + dst;
    int bin = key / BPB;
    int pos = atomicAdd(&cur[bin], 1);
    binned[pos] = ((unsigned)(key - bin * BPB) << 17) | (unsigned)src;
  }
}

// p46: per bin, fused deg4 + bucket-hist + local CSR scan + slot scatter.
// 1024 threads (16 waves) for the same occupancy reason as p3.
__global__ __launch_bounds__(1024) void p46_kernel(
    const unsigned* __restrict__ binned, const int* __restrict__ bincur,
    int* __restrict__ deg4, int* __restrict__ S, int* __restrict__ slots,
    int* __restrict__ bcnt) {
  __shared__ int hist[BPB];
  __shared__ int cur[BPB];
  __shared__ int bh[84];
  __shared__ int wtot[16];
  int t = threadIdx.x, bin = blockIdx.x;
  int kb = bin * BPB;
  for (int i = t; i < BPB; i += 1024) hist[i] = 0;
  if (t < 84) bh[t] = 0;
  __syncthreads();
  int start = bin << BINCAP_LOG;
  int end = bincur[bin];
  for (int i = start + t; i < end; i += 1024)
    atomicAdd(&hist[binned[i] >> 17], 1);
  __syncthreads();
  for (int i = t; i < BPB; i += 1024) {
    int key = kb + i;
    if (key < MKEYS) {
      int d = hist[i];
      deg4[key] = d;
      int j = key / N_NODES;
      int b = d < MAX_DEG ? d : MAX_DEG;
      atomicAdd(&bh[j * 21 + b], 1);
    }
  }
  int base = t * 4;
  int v0 = 0, v1 = 0, v2 = 0, v3 = 0;
  if (base < BPB) {
    v0 = hist[base];
    v1 = (base + 1 < BPB) ? hist[base + 1] : 0;
    v2 = (base + 2 < BPB) ? hist[base + 2] : 0;
    v3 = (base + 3 < BPB) ? hist[base + 3] : 0;
  }
  int s = v0 + v1 + v2 + v3;
  int incl = s;
#pragma unroll
  for (int off = 1; off < 64; off <<= 1) {
    int y = __shfl_up(incl, off, 64);
    if ((t & 63) >= off) incl += y;
  }
  if ((t & 63) == 63) wtot[t >> 6] = incl;
  __syncthreads();
  int wbase = 0;
  for (int w = 0; w < (t >> 6); ++w) wbase += wtot[w];
  int ex = start + wbase + incl - s;
  if (base < BPB) {
    cur[base] = ex;
    if (base + 1 < BPB) cur[base + 1] = ex + v0;
    if (base + 2 < BPB) cur[base + 2] = ex + v0 + v1;
    if (base + 3 < BPB) cur[base + 3] = ex + v0 + v1 + v2;
  }
  __syncthreads();
  for (int i = t; i < BPB; i += 1024)
    if (kb + i < MKEYS) S[kb + i] = cur[i];
  if (t < 84 && bh[t]) atomicAdd(&bcnt[t], bh[t]);
  __syncthreads();
  for (int i = start + t; i < end; i += 1024) {
    unsigned v = binned[i];
    int pos = atomicAdd(&cur[v >> 17], 1);
    slots[pos] = (int)(v & 0x1ffffu);
  }
}

// ---------------- bucket scan + tile descriptors (one block) ----------------
__global__ __launch_bounds__(128) void bucket_scan(
    const int* __restrict__ bcnt, int* __restrict__ boff, int* __restrict__ bcur,
    int* __restrict__ ntiles, int* __restrict__ tdesc) {
  __shared__ int wt[2];
  __shared__ int exL[84], cntL[84], toffL[84];
  int t = threadIdx.x;
  int v = (t < 84) ? bcnt[t] : 0;
  int incl = v;
#pragma unroll
  for (int off = 1; off < 64; off <<= 1) {
    int y = __shfl_up(incl, off, 64);
    if ((t & 63) >= off) incl += y;
  }
  if ((t & 63) == 63) wt[t >> 6] = incl;
  __syncthreads();
  int wbase = (t >> 6) ? wt[0] : 0;
  if (t < 84) {
    int ex = wbase + incl - v;
    boff[t] = ex;
    bcur[t] = ex;
    exL[t] = ex;
    cntL[t] = v;
  }
  __syncthreads();
  if (t < 4) {
    int acc = 0;
    for (int bb = 0; bb < 21; ++bb) {
      toffL[t * 21 + bb] = acc;
      acc += (cntL[t * 21 + bb] + 63) >> 6;
    }
    ntiles[t] = acc;
  }
  __syncthreads();
  for (int jb = 0; jb < 84; ++jb) {
    int j = jb / 21, b = jb - j * 21;
    int cnt = cntL[jb], off = exL[jb], tb = toffL[jb];
    int nt = (cnt + 63) >> 6;
    for (int i = t; i < nt; i += 128) {
      int s2 = i << 6;
      int nIn = min(64, cnt - s2);
      tdesc[j * MAX_TILES + tb + i] = ((off + s2) << 12) | (b << 7) | nIn;
    }
  }
}

__global__ __launch_bounds__(256) void bucket_fill(
    const int* __restrict__ deg4, int* __restrict__ bcur, int* __restrict__ blist) {
  __shared__ int hist[21];
  __shared__ int base[21];
  int t = threadIdx.x;
  if (t < 21) hist[t] = 0;
  __syncthreads();
  int node = blockIdx.x * 256 + t;
  int j = blockIdx.y;
  int b = 0, lpos = 0;
  bool valid = (node < N_NODES);
  if (valid) {
    int d = deg4[j * N_NODES + node];
    b = d < MAX_DEG ? d : MAX_DEG;
    lpos = atomicAdd(&hist[b], 1);
  }
  __syncthreads();
  if (t < 21 && hist[t]) base[t] = atomicAdd(&bcur[j * 21 + t], hist[t]);
  __syncthreads();
  if (valid) blist[base[b] + lpos] = node;
}

// ---------------- FUSED conv: quad-per-row gather + MFMA, zero barriers -----
__global__ __launch_bounds__(256) void conv_kernel(
    float* __restrict__ h, unsigned short* __restrict__ ab,
    const int* __restrict__ S, const int* __restrict__ deg,
    const int* __restrict__ slots,
    const int* __restrict__ blist, const int* __restrict__ tdesc,
    const int* __restrict__ ntiles, const unsigned short* __restrict__ wbt,
    const float* __restrict__ bl, int j, int inoff, int do_relu, int last) {
  if ((int)blockIdx.x >= ntiles[j]) return;
  int d = tdesc[j * MAX_TILES + blockIdx.x];
  int nIn = d & 127;
  int b = (d >> 7) & 31;
  const int* lst = blist + (d >> 12);
  int outoff = 64 - inoff;

  int tid = threadIdx.x;
  int qw = tid >> 6, lane = tid & 63;

  if (b == 0) {
    for (int r = qw * 16; r < qw * 16 + 16; ++r) {
      if (r < nIn) {
        int node = lst[r];
        float v = b2f(ab[node * 128 + inoff + lane]);
        if (do_relu) v = fmaxf(v, 0.f);
        if (last) {
          if (node < G_NODES) h[node * H + lane] = v;
        } else {
          ab[node * 128 + outoff + lane] = f2b(v);
        }
      }
    }
    return;
  }

  __shared__ unsigned short aL[64 * 136];  // 17408 B; reused as fp32[64*68]
  __shared__ int nodeS[64];
  int q = lane >> 4, cl = lane & 15;

  for (int i = 0; i < 4; ++i) {
    int r = qw * 16 + q * 4 + i;
    int node = (r < nIn) ? lst[r] : -1;
    if (cl == 0) nodeS[r] = node;
    uint2 selfv = make_uint2(0u, 0u);
    float s0a = 0.f, s1a = 0.f, s2a = 0.f, s3a = 0.f;
    float s0b = 0.f, s1b = 0.f, s2b = 0.f, s3b = 0.f;
    if (node >= 0) {
      selfv = *(const uint2*)&ab[node * 128 + inoff + 4 * cl];
      int off = S[node];
      int dg = (b < MAX_DEG) ? b : deg[node];
      int e = 0;
      for (; e + 3 < dg; e += 4) {
        int n0 = slots[off + e];
        int n1 = slots[off + e + 1];
        int n2 = slots[off + e + 2];
        int n3 = slots[off + e + 3];
        uint2 p0 = *(const uint2*)&ab[n0 * 128 + inoff + 4 * cl];
        uint2 p1 = *(const uint2*)&ab[n1 * 128 + inoff + 4 * cl];
        uint2 p2 = *(const uint2*)&ab[n2 * 128 + inoff + 4 * cl];
        uint2 p3 = *(const uint2*)&ab[n3 * 128 + inoff + 4 * cl];
        s0a += b2f((unsigned short)p0.x) + b2f((unsigned short)p1.x);
        s0b += b2f((unsigned short)p2.x) + b2f((unsigned short)p3.x);
        s1a += b2f((unsigned short)(p0.x >> 16)) + b2f((unsigned short)(p1.x >> 16));
        s1b += b2f((unsigned short)(p2.x >> 16)) + b2f((unsigned short)(p3.x >> 16));
        s2a += b2f((unsigned short)p0.y) + b2f((unsigned short)p1.y);
        s2b += b2f((unsigned short)p2.y) + b2f((unsigned short)p3.y);
        s3a += b2f((unsigned short)(p0.y >> 16)) + b2f((unsigned short)(p1.y >> 16));
        s3b += b2f((unsigned short)(p2.y >> 16)) + b2f((unsigned short)(p3.y >> 16));
      }
      for (; e < dg; ++e) {
        uint2 p0 = *(const uint2*)&ab[slots[off + e] * 128 + inoff + 4 * cl];
        s0a += b2f((unsigned short)p0.x);
        s1a += b2f((unsigned short)(p0.x >> 16));
        s2a += b2f((unsigned short)p0.y);
        s3a += b2f((unsigned short)(p0.y >> 16));
      }
    }
    uint2 o;
    o.x = (unsigned)f2b(s0a + s0b) | ((unsigned)f2b(s1a + s1b) << 16);
    o.y = (unsigned)f2b(s2a + s2b) | ((unsigned)f2b(s3a + s3b) << 16);
    *(uint2*)&aL[r * 136 + 4 * cl] = o;           // hsum -> k 0:64
    *(uint2*)&aL[r * 136 + 64 + 4 * cl] = selfv;  // self -> k 64:128
  }
  // no barrier: wave reads only its own rows below

  int m = lane & 15, quad = lane >> 4;
  const unsigned short* wbase = wbt + (size_t)(j * 21 + b) * 64 * 128;
  float4v acc[4];
#pragma unroll
  for (int t = 0; t < 4; ++t) {
    float bv = bl[b * 64 + t * 16 + m];
    acc[t] = (float4v){bv, bv, bv, bv};
  }
#pragma unroll
  for (int ks = 0; ks < 4; ++ks) {
    short8 a = *(const short8*)&aL[(qw * 16 + m) * 136 + ks * 32 + quad * 8];
#pragma unroll
    for (int t = 0; t < 4; ++t) {
      short8 bf = *(const short8*)&wbase[(t * 16 + m) * 128 + ks * 32 + quad * 8];
      acc[t] = __builtin_amdgcn_mfma_f32_16x16x32_bf16(a, bf, acc[t], 0, 0, 0);
    }
  }
  if (do_relu) {
#pragma unroll
    for (int t = 0; t < 4; ++t)
#pragma unroll
      for (int r = 0; r < 4; ++r) acc[t][r] = fmaxf(acc[t][r], 0.f);
  }
  float* outF = (float*)aL;
#pragma unroll
  for (int t = 0; t < 4; ++t)
#pragma unroll
    for (int r = 0; r < 4; ++r)
      outF[(qw * 16 + quad * 4 + r) * 68 + t * 16 + m] = acc[t][r];
  if (last) {
    for (int r = qw * 16; r < qw * 16 + 16; ++r)
      if (r < nIn && nodeS[r] < G_NODES)
        h[nodeS[r] * H + lane] = outF[r * 68 + lane];
  } else {
    for (int r = qw * 16; r < qw * 16 + 16; ++r)
      if (r < nIn) ab[nodeS[r] * 128 + outoff + lane] = f2b(outF[r * 68 + lane]);
  }
}

// ---------------- fused LN + residual + pool + (last block) output head -----
// Last finishing block computes out = pooled @ out_w + out_b; pooled is read
// with agent-scope atomic loads (bypasses non-coherent L1/L2 copies).
__global__ __launch_bounds__(1024) void ln_pool_kernel(
    const float* __restrict__ h, const float* __restrict__ h0,
    const float* __restrict__ g, const float* __restrict__ b,
    const int* __restrict__ batch, float* __restrict__ pooled,
    const float* __restrict__ ow, const float* __restrict__ ob,
    float* __restrict__ out, int* __restrict__ done) {
  __shared__ float sm[NUM_GRAPHS * H];  // 32 KB
  __shared__ int lastS;
  int t = threadIdx.x;
  for (int i = t; i < NUM_GRAPHS * H; i += 1024) sm[i] = 0.f;
  __syncthreads();
  int lane = t & 63, w = t >> 6;  // 16 waves
  const int per = (G_NODES + POOL_BLOCKS - 1) / POOL_BLOCKS;
  int start = blockIdx.x * per;
  int end = min(start + per, G_NODES);
  for (int node = start + w; node < end; node += 16) {
    int idx = node * H + lane;
    float v = h[idx];
    float s = v;
#pragma unroll
    for (int off = 32; off > 0; off >>= 1) s += __shfl_xor(s, off, 64);
    float mu = s * (1.0f / H);
    float dv = v - mu;
    float q = dv * dv;
#pragma unroll
    for (int off = 32; off > 0; off >>= 1) q += __shfl_xor(q, off, 64);
    float inv = rsqrtf(q * (1.0f / H) + LN_EPS);
    float r = dv * inv * g[lane] + b[lane] + h0[idx];
    atomicAdd(&sm[batch[node] * H + lane], r);
  }
  __syncthreads();
  for (int i = t; i < NUM_GRAPHS * H; i += 1024) {
    float v = sm[i];
    if (v != 0.f) atomicAdd(&pooled[i], v);
  }
  __syncthreads();  // barrier drains this block's vmem (atomics complete)
  __threadfence();
  if (t == 0) lastS = atomicAdd(done, 1);
  __syncthreads();
  if (lastS == POOL_BLOCKS - 1) {
    for (int gph = w; gph < NUM_GRAPHS; gph += 16) {
      float v = __hip_atomic_load(&pooled[gph * H + lane], __ATOMIC_RELAXED,
                                  __HIP_MEMORY_SCOPE_AGENT) * ow[lane];
#pragma unroll
      for (int off = 32; off > 0; off >>= 1) v += __shfl_xor(v, off, 64);
      if (lane == 0) out[gph] = v + ob[0];
    }
  }
}

extern "C" void kernel_launch(void* const* d_in, const int* in_sizes, int n_in,
                              void* d_out, int out_size, void* d_ws, size_t ws_size,
                              hipStream_t stream) {
  const float* x       = (const float*)d_in[0];
  const int*   ei_edge = (const int*)d_in[1];
  const int*   ei_sub  = (const int*)d_in[2];
  const int*   ei_ns   = (const int*)d_in[3];
  const int*   ei_sn   = (const int*)d_in[4];
  const int*   batch   = (const int*)d_in[7];
  const float* emb_w   = (const float*)d_in[8];
  const float* emb_b   = (const float*)d_in[9];
  const float* conv_wl = (const float*)d_in[10];
  const float* conv_bl = (const float*)d_in[11];
  const float* conv_wr = (const float*)d_in[12];
  const float* ln_g    = (const float*)d_in[13];
  const float* ln_b    = (const float*)d_in[14];
  const float* out_w   = (const float*)d_in[15];
  const float* out_b   = (const float*)d_in[16];
  float* out = (float*)d_out;

  const size_t HB = (size_t)N_NODES * H * sizeof(float);   // 25.6 MB
  char* ws = (char*)d_ws;
  float* h      = (float*)(ws);                        // fp32, ground, j==3
  float* h0     = (float*)(ws + HB);                   // fp32 residual (ground)
  unsigned short* ab = (unsigned short*)(ws + 2 * HB); // [node][128] bf16 25.6MB
  // Persistent build outputs:
  int*   deg4   = (int*)(ws + 3 * HB);                           // 1.6 MB
  int*   S      = (int*)(ws + 78400000);                         // 1.6 MB
  int*   bcnt   = (int*)(ws + 92800000);
  int*   boff   = (int*)(ws + 92800512);
  int*   bcur   = (int*)(ws + 92801024);
  int*   blist  = (int*)(ws + 92801536);                         // 1.6 MB
  float* pooled = (float*)(ws + 94401536);                       // 32 KB
  unsigned short* wbt = (unsigned short*)(ws + 94434304);        // 1.38 MB
  int*   tdesc  = (int*)(ws + 95810560);                         // 25.6 KB
  int*   ntiles = (int*)(ws + 95836160);                         // 16 B
  unsigned short* ewbt = (unsigned short*)(ws + 95836608);       // 4 KB
  int*   bincur = (int*)(ws + 95841024);                         // 2 KB
  int*   done   = (int*)(ws + 95843072);                         // 4 B
  // Fixed-capacity bin regions (ws_size ~= 256 MiB, plenty of headroom):
  unsigned* binned = (unsigned*)(ws + 100000000);                // 16.8 MB
  int*   slots  = (int*)(ws + 117000000);                        // 16.8 MB

  const int* e0 = ei_edge, *e1 = ei_ns, *e2 = ei_sub, *e3 = ei_sn;

  // --- build ---
  wconv_kernel<<<(84 * 64 * 128 + H * F_IN + 255) / 256, 256, 0, stream>>>(
      conv_wl, conv_wr, emb_w, wbt, ewbt, bincur, bcnt, done);
  p3_binscatter<<<NBINS, 1024, 0, stream>>>(e0, e1, e2, e3, bincur, binned);
  p46_kernel<<<NBINS, 1024, 0, stream>>>(binned, bincur, deg4, S, slots, bcnt);
  bucket_scan<<<1, 128, 0, stream>>>(bcnt, boff, bcur, ntiles, tdesc);
  bucket_fill<<<dim3((N_NODES + 255) / 256, 4), 256, 0, stream>>>(deg4, bcur, blist);

  // --- network (self half ping-pongs 64 -> 0 -> 64 -> 0 -> h) ---
  emb_kernel<<<(N_NODES + 63) / 64, 256, 0, stream>>>(x, ewbt, emb_b, h0, ab, pooled);

  for (int j = 0; j < 4; ++j) {
    conv_kernel<<<MAX_TILES, 256, 0, stream>>>(
        h, ab, S + j * N_NODES, deg4 + j * N_NODES, slots,
        blist, tdesc, ntiles, wbt,
        conv_bl + (size_t)j * 21 * H, j,
        (j & 1) ? 0 : 64,          // inoff
        j < 3 ? 1 : 0, j == 3 ? 1 : 0);
  }

  ln_pool_kernel<<<POOL_BLOCKS, 1024, 0, stream>>>(
      h, h0, ln_g, ln_b, batch, pooled, out_w, out_b, out, done);
}

// Round 18
// 371.462 us; speedup vs baseline: 1.1549x; 1.1549x over previous
//
#include <hip/hip_runtime.h>

#define N_NODES 100000
#define G_NODES 50000
#define N_EDGES 800000
#define H 64
#define F_IN 32
#define MAX_DEG 20
#define NUM_GRAPHS 128
#define LN_EPS 1e-5f
#define POOL_BLOCKS 256
#define MAX_TILES 1600

// Binned CSR build: 512 bins over the 4*N key space, FIXED 8192-entry
// capacity per bin (mean 6250, sigma~79 -> +24 sigma, unreachable).
#define NBINS 512
#define BPB 782            // keys per bin: 782*512 = 400384 >= 400000
#define BINCAP_LOG 13      // 8192 entries per bin
#define CHUNK 6250         // edges per build block: 6250*512 = 3.2M
#define MKEYS (4 * N_NODES)
#define MEDGES (4 * N_EDGES)

typedef __attribute__((ext_vector_type(8))) short short8;
typedef __attribute__((ext_vector_type(4))) float float4v;

// bf16 helpers (RNE), no header dependency
static __device__ __forceinline__ unsigned short f2b(float f) {
  unsigned u = __float_as_uint(f);
  return (unsigned short)((u + 0x7fffu + ((u >> 16) & 1u)) >> 16);
}
static __device__ __forceinline__ float b2f(unsigned short b) {
  return __uint_as_float(((unsigned)b) << 16);
}

// ---------------- weight preconvert + cursor/bcnt init (runs FIRST) ---------
__global__ __launch_bounds__(256) void wconv_kernel(
    const float* __restrict__ wl, const float* __restrict__ wr,
    const float* __restrict__ ew, unsigned short* __restrict__ wbt,
    unsigned short* __restrict__ ewbt, int* __restrict__ bincur,
    int* __restrict__ bcnt) {
  int i = blockIdx.x * 256 + threadIdx.x;
  if (blockIdx.x == 0) {
    for (int k = threadIdx.x; k < NBINS; k += 256) bincur[k] = k << BINCAP_LOG;
    if (threadIdx.x < 84) bcnt[threadIdx.x] = 0;
  }
  if (i < 84 * 64 * 128) {
    int k = i & 127;
    int ch = (i >> 7) & 63;
    int jb = i >> 13;
    float v = (k < 64) ? wl[jb * 4096 + k * 64 + ch]
                       : wr[jb * 4096 + (k - 64) * 64 + ch];
    wbt[i] = f2b(v);
  } else if (i < 84 * 64 * 128 + H * F_IN) {
    int ii = i - 84 * 64 * 128;
    int c = ii >> 5, f = ii & 31;
    ewbt[ii] = f2b(ew[f * H + c]);
  }
}

// ---------------- MFMA embedding + pooled zero-init -------------------------
__global__ __launch_bounds__(256) void emb_kernel(
    const float* __restrict__ x, const unsigned short* __restrict__ ewbt,
    const float* __restrict__ eb, float* __restrict__ h0,
    unsigned short* __restrict__ ab, float* __restrict__ pooled) {
  int tid = threadIdx.x;
  if (blockIdx.x == 0) {
    for (int i = tid; i < NUM_GRAPHS * H; i += 256) pooled[i] = 0.f;
  }
  int base = blockIdx.x * 64;
  int nIn = min(64, N_NODES - base);
  int qw = tid >> 6, lane = tid & 63;
  __shared__ unsigned short aL[64 * 40];  // stride 40 breaks pow2 banks
  __shared__ float outF[64 * 68];

  {
    int node = tid >> 2, chb = (tid & 3) * 8;
    unsigned short v8[8];
    if (node < nIn) {
      const float* xr = x + ((size_t)(base + node)) * F_IN + chb;
      float4 f0 = *(const float4*)(xr);
      float4 f1 = *(const float4*)(xr + 4);
      v8[0] = f2b(f0.x); v8[1] = f2b(f0.y); v8[2] = f2b(f0.z); v8[3] = f2b(f0.w);
      v8[4] = f2b(f1.x); v8[5] = f2b(f1.y); v8[6] = f2b(f1.z); v8[7] = f2b(f1.w);
    } else {
#pragma unroll
      for (int i = 0; i < 8; ++i) v8[i] = 0;
    }
    *(short8*)&aL[(tid >> 2) * 40 + chb] = *(short8*)v8;
  }
  // no __syncthreads: wave qw staged exactly rows [qw*16, qw*16+16)

  int m = lane & 15, quad = lane >> 4;
  short8 a = *(const short8*)&aL[(qw * 16 + m) * 40 + quad * 8];
  float4v acc[4];
#pragma unroll
  for (int t = 0; t < 4; ++t) {
    float bv = eb[t * 16 + m];
    acc[t] = (float4v){bv, bv, bv, bv};
  }
#pragma unroll
  for (int t = 0; t < 4; ++t) {
    short8 bf = *(const short8*)&ewbt[(t * 16 + m) * F_IN + quad * 8];
    acc[t] = __builtin_amdgcn_mfma_f32_16x16x32_bf16(a, bf, acc[t], 0, 0, 0);
  }
#pragma unroll
  for (int t = 0; t < 4; ++t)
#pragma unroll
    for (int r = 0; r < 4; ++r)
      outF[(qw * 16 + quad * 4 + r) * 68 + t * 16 + m] = acc[t][r];
  for (int r = qw * 16; r < qw * 16 + 16; ++r) {
    if (r < nIn) {
      int node = base + r;
      float v = outF[r * 68 + lane];
      if (node < G_NODES) h0[node * H + lane] = v;
      ab[node * 128 + 64 + lane] = f2b(v);
    }
  }
}

// ---------------- single-pass binning, 1024 threads (R16: 16.9% occ fix) ----
__global__ __launch_bounds__(1024) void p3_binscatter(
    const int* __restrict__ e0, const int* __restrict__ e1,
    const int* __restrict__ e2, const int* __restrict__ e3,
    int* __restrict__ bincur, unsigned* __restrict__ binned) {
  __shared__ int hist[NBINS];
  __shared__ int cur[NBINS];
  int t = threadIdx.x, b = blockIdx.x;
  for (int i = t; i < NBINS; i += 1024) hist[i] = 0;
  __syncthreads();
  int j = b >> 7;
  const int* ei = (j == 0) ? e0 : (j == 1) ? e1 : (j == 2) ? e2 : e3;
  int ebase = (b & 127) * CHUNK;
  for (int i = t; i < CHUNK; i += 1024) {
    int dst = ei[N_EDGES + ebase + i];
    atomicAdd(&hist[(j * N_NODES + dst) / BPB], 1);
  }
  __syncthreads();
  for (int i = t; i < NBINS; i += 1024) {
    int c = hist[i];
    cur[i] = c ? atomicAdd(&bincur[i], c) : 0;
  }
  __syncthreads();
  for (int i = t; i < CHUNK; i += 1024) {
    int src = ei[ebase + i];
    int dst = ei[N_EDGES + ebase + i];
    int key = j * N_NODES + dst;
    int bin = key / BPB;
    int pos = atomicAdd(&cur[bin], 1);
    binned[pos] = ((unsigned)(key - bin * BPB) << 17) | (unsigned)src;
  }
}

// p46: per bin, fused deg4 + bucket-hist + local CSR scan + slot scatter.
__global__ __launch_bounds__(1024) void p46_kernel(
    const unsigned* __restrict__ binned, const int* __restrict__ bincur,
    int* __restrict__ deg4, int* __restrict__ S, int* __restrict__ slots,
    int* __restrict__ bcnt) {
  __shared__ int hist[BPB];
  __shared__ int cur[BPB];
  __shared__ int bh[84];
  __shared__ int wtot[16];
  int t = threadIdx.x, bin = blockIdx.x;
  int kb = bin * BPB;
  for (int i = t; i < BPB; i += 1024) hist[i] = 0;
  if (t < 84) bh[t] = 0;
  __syncthreads();
  int start = bin << BINCAP_LOG;
  int end = bincur[bin];
  for (int i = start + t; i < end; i += 1024)
    atomicAdd(&hist[binned[i] >> 17], 1);
  __syncthreads();
  for (int i = t; i < BPB; i += 1024) {
    int key = kb + i;
    if (key < MKEYS) {
      int d = hist[i];
      deg4[key] = d;
      int j = key / N_NODES;
      int b = d < MAX_DEG ? d : MAX_DEG;
      atomicAdd(&bh[j * 21 + b], 1);
    }
  }
  int base = t * 4;
  int v0 = 0, v1 = 0, v2 = 0, v3 = 0;
  if (base < BPB) {
    v0 = hist[base];
    v1 = (base + 1 < BPB) ? hist[base + 1] : 0;
    v2 = (base + 2 < BPB) ? hist[base + 2] : 0;
    v3 = (base + 3 < BPB) ? hist[base + 3] : 0;
  }
  int s = v0 + v1 + v2 + v3;
  int incl = s;
#pragma unroll
  for (int off = 1; off < 64; off <<= 1) {
    int y = __shfl_up(incl, off, 64);
    if ((t & 63) >= off) incl += y;
  }
  if ((t & 63) == 63) wtot[t >> 6] = incl;
  __syncthreads();
  int wbase = 0;
  for (int w = 0; w < (t >> 6); ++w) wbase += wtot[w];
  int ex = start + wbase + incl - s;
  if (base < BPB) {
    cur[base] = ex;
    if (base + 1 < BPB) cur[base + 1] = ex + v0;
    if (base + 2 < BPB) cur[base + 2] = ex + v0 + v1;
    if (base + 3 < BPB) cur[base + 3] = ex + v0 + v1 + v2;
  }
  __syncthreads();
  for (int i = t; i < BPB; i += 1024)
    if (kb + i < MKEYS) S[kb + i] = cur[i];
  if (t < 84 && bh[t]) atomicAdd(&bcnt[t], bh[t]);
  __syncthreads();
  for (int i = start + t; i < end; i += 1024) {
    unsigned v = binned[i];
    int pos = atomicAdd(&cur[v >> 17], 1);
    slots[pos] = (int)(v & 0x1ffffu);
  }
}

// ---------------- bucket scan + tile descriptors (one block) ----------------
__global__ __launch_bounds__(128) void bucket_scan(
    const int* __restrict__ bcnt, int* __restrict__ boff, int* __restrict__ bcur,
    int* __restrict__ ntiles, int* __restrict__ tdesc) {
  __shared__ int wt[2];
  __shared__ int exL[84], cntL[84], toffL[84];
  int t = threadIdx.x;
  int v = (t < 84) ? bcnt[t] : 0;
  int incl = v;
#pragma unroll
  for (int off = 1; off < 64; off <<= 1) {
    int y = __shfl_up(incl, off, 64);
    if ((t & 63) >= off) incl += y;
  }
  if ((t & 63) == 63) wt[t >> 6] = incl;
  __syncthreads();
  int wbase = (t >> 6) ? wt[0] : 0;
  if (t < 84) {
    int ex = wbase + incl - v;
    boff[t] = ex;
    bcur[t] = ex;
    exL[t] = ex;
    cntL[t] = v;
  }
  __syncthreads();
  if (t < 4) {
    int acc = 0;
    for (int bb = 0; bb < 21; ++bb) {
      toffL[t * 21 + bb] = acc;
      acc += (cntL[t * 21 + bb] + 63) >> 6;
    }
    ntiles[t] = acc;
  }
  __syncthreads();
  for (int jb = 0; jb < 84; ++jb) {
    int j = jb / 21, b = jb - j * 21;
    int cnt = cntL[jb], off = exL[jb], tb = toffL[jb];
    int nt = (cnt + 63) >> 6;
    for (int i = t; i < nt; i += 128) {
      int s2 = i << 6;
      int nIn = min(64, cnt - s2);
      tdesc[j * MAX_TILES + tb + i] = ((off + s2) << 12) | (b << 7) | nIn;
    }
  }
}

__global__ __launch_bounds__(256) void bucket_fill(
    const int* __restrict__ deg4, int* __restrict__ bcur, int* __restrict__ blist) {
  __shared__ int hist[21];
  __shared__ int base[21];
  int t = threadIdx.x;
  if (t < 21) hist[t] = 0;
  __syncthreads();
  int node = blockIdx.x * 256 + t;
  int j = blockIdx.y;
  int b = 0, lpos = 0;
  bool valid = (node < N_NODES);
  if (valid) {
    int d = deg4[j * N_NODES + node];
    b = d < MAX_DEG ? d : MAX_DEG;
    lpos = atomicAdd(&hist[b], 1);
  }
  __syncthreads();
  if (t < 21 && hist[t]) base[t] = atomicAdd(&bcur[j * 21 + t], hist[t]);
  __syncthreads();
  if (valid) blist[base[b] + lpos] = node;
}

// ---------------- FUSED conv: quad-per-row gather + MFMA, zero barriers -----
__global__ __launch_bounds__(256) void conv_kernel(
    float* __restrict__ h, unsigned short* __restrict__ ab,
    const int* __restrict__ S, const int* __restrict__ deg,
    const int* __restrict__ slots,
    const int* __restrict__ blist, const int* __restrict__ tdesc,
    const int* __restrict__ ntiles, const unsigned short* __restrict__ wbt,
    const float* __restrict__ bl, int j, int inoff, int do_relu, int last) {
  if ((int)blockIdx.x >= ntiles[j]) return;
  int d = tdesc[j * MAX_TILES + blockIdx.x];
  int nIn = d & 127;
  int b = (d >> 7) & 31;
  const int* lst = blist + (d >> 12);
  int outoff = 64 - inoff;

  int tid = threadIdx.x;
  int qw = tid >> 6, lane = tid & 63;

  if (b == 0) {
    for (int r = qw * 16; r < qw * 16 + 16; ++r) {
      if (r < nIn) {
        int node = lst[r];
        float v = b2f(ab[node * 128 + inoff + lane]);
        if (do_relu) v = fmaxf(v, 0.f);
        if (last) {
          if (node < G_NODES) h[node * H + lane] = v;
        } else {
          ab[node * 128 + outoff + lane] = f2b(v);
        }
      }
    }
    return;
  }

  __shared__ unsigned short aL[64 * 136];  // 17408 B; reused as fp32[64*68]
  __shared__ int nodeS[64];
  int q = lane >> 4, cl = lane & 15;

  for (int i = 0; i < 4; ++i) {
    int r = qw * 16 + q * 4 + i;
    int node = (r < nIn) ? lst[r] : -1;
    if (cl == 0) nodeS[r] = node;
    uint2 selfv = make_uint2(0u, 0u);
    float s0a = 0.f, s1a = 0.f, s2a = 0.f, s3a = 0.f;
    float s0b = 0.f, s1b = 0.f, s2b = 0.f, s3b = 0.f;
    if (node >= 0) {
      selfv = *(const uint2*)&ab[node * 128 + inoff + 4 * cl];
      int off = S[node];
      int dg = (b < MAX_DEG) ? b : deg[node];
      int e = 0;
      for (; e + 3 < dg; e += 4) {
        int n0 = slots[off + e];
        int n1 = slots[off + e + 1];
        int n2 = slots[off + e + 2];
        int n3 = slots[off + e + 3];
        uint2 p0 = *(const uint2*)&ab[n0 * 128 + inoff + 4 * cl];
        uint2 p1 = *(const uint2*)&ab[n1 * 128 + inoff + 4 * cl];
        uint2 p2 = *(const uint2*)&ab[n2 * 128 + inoff + 4 * cl];
        uint2 p3 = *(const uint2*)&ab[n3 * 128 + inoff + 4 * cl];
        s0a += b2f((unsigned short)p0.x) + b2f((unsigned short)p1.x);
        s0b += b2f((unsigned short)p2.x) + b2f((unsigned short)p3.x);
        s1a += b2f((unsigned short)(p0.x >> 16)) + b2f((unsigned short)(p1.x >> 16));
        s1b += b2f((unsigned short)(p2.x >> 16)) + b2f((unsigned short)(p3.x >> 16));
        s2a += b2f((unsigned short)p0.y) + b2f((unsigned short)p1.y);
        s2b += b2f((unsigned short)p2.y) + b2f((unsigned short)p3.y);
        s3a += b2f((unsigned short)(p0.y >> 16)) + b2f((unsigned short)(p1.y >> 16));
        s3b += b2f((unsigned short)(p2.y >> 16)) + b2f((unsigned short)(p3.y >> 16));
      }
      for (; e < dg; ++e) {
        uint2 p0 = *(const uint2*)&ab[slots[off + e] * 128 + inoff + 4 * cl];
        s0a += b2f((unsigned short)p0.x);
        s1a += b2f((unsigned short)(p0.x >> 16));
        s2a += b2f((unsigned short)p0.y);
        s3a += b2f((unsigned short)(p0.y >> 16));
      }
    }
    uint2 o;
    o.x = (unsigned)f2b(s0a + s0b) | ((unsigned)f2b(s1a + s1b) << 16);
    o.y = (unsigned)f2b(s2a + s2b) | ((unsigned)f2b(s3a + s3b) << 16);
    *(uint2*)&aL[r * 136 + 4 * cl] = o;           // hsum -> k 0:64
    *(uint2*)&aL[r * 136 + 64 + 4 * cl] = selfv;  // self -> k 64:128
  }
  // no barrier: wave reads only its own rows below

  int m = lane & 15, quad = lane >> 4;
  const unsigned short* wbase = wbt + (size_t)(j * 21 + b) * 64 * 128;
  float4v acc[4];
#pragma unroll
  for (int t = 0; t < 4; ++t) {
    float bv = bl[b * 64 + t * 16 + m];
    acc[t] = (float4v){bv, bv, bv, bv};
  }
#pragma unroll
  for (int ks = 0; ks < 4; ++ks) {
    short8 a = *(const short8*)&aL[(qw * 16 + m) * 136 + ks * 32 + quad * 8];
#pragma unroll
    for (int t = 0; t < 4; ++t) {
      short8 bf = *(const short8*)&wbase[(t * 16 + m) * 128 + ks * 32 + quad * 8];
      acc[t] = __builtin_amdgcn_mfma_f32_16x16x32_bf16(a, bf, acc[t], 0, 0, 0);
    }
  }
  if (do_relu) {
#pragma unroll
    for (int t = 0; t < 4; ++t)
#pragma unroll
      for (int r = 0; r < 4; ++r) acc[t][r] = fmaxf(acc[t][r], 0.f);
  }
  float* outF = (float*)aL;
#pragma unroll
  for (int t = 0; t < 4; ++t)
#pragma unroll
    for (int r = 0; r < 4; ++r)
      outF[(qw * 16 + quad * 4 + r) * 68 + t * 16 + m] = acc[t][r];
  if (last) {
    for (int r = qw * 16; r < qw * 16 + 16; ++r)
      if (r < nIn && nodeS[r] < G_NODES)
        h[nodeS[r] * H + lane] = outF[r * 68 + lane];
  } else {
    for (int r = qw * 16; r < qw * 16 + 16; ++r)
      if (r < nIn) ab[nodeS[r] * 128 + outoff + lane] = f2b(outF[r * 68 + lane]);
  }
}

// ---------------- fused layernorm + residual + ground-node pool -------------
// R17 lesson: fusing the output head via done-counter + __threadfence cost
// 78us (grid-wide device-scope fence by every thread). Plain version + tiny
// out_kernel dispatch is far cheaper.
__global__ __launch_bounds__(1024) void ln_pool_kernel(
    const float* __restrict__ h, const float* __restrict__ h0,
    const float* __restrict__ g, const float* __restrict__ b,
    const int* __restrict__ batch, float* __restrict__ pooled) {
  __shared__ float sm[NUM_GRAPHS * H];  // 32 KB
  int t = threadIdx.x;
  for (int i = t; i < NUM_GRAPHS * H; i += 1024) sm[i] = 0.f;
  __syncthreads();
  int lane = t & 63, w = t >> 6;  // 16 waves
  const int per = (G_NODES + POOL_BLOCKS - 1) / POOL_BLOCKS;
  int start = blockIdx.x * per;
  int end = min(start + per, G_NODES);
  for (int node = start + w; node < end; node += 16) {
    int idx = node * H + lane;
    float v = h[idx];
    float s = v;
#pragma unroll
    for (int off = 32; off > 0; off >>= 1) s += __shfl_xor(s, off, 64);
    float mu = s * (1.0f / H);
    float dv = v - mu;
    float q = dv * dv;
#pragma unroll
    for (int off = 32; off > 0; off >>= 1) q += __shfl_xor(q, off, 64);
    float inv = rsqrtf(q * (1.0f / H) + LN_EPS);
    float r = dv * inv * g[lane] + b[lane] + h0[idx];
    atomicAdd(&sm[batch[node] * H + lane], r);
  }
  __syncthreads();
  for (int i = t; i < NUM_GRAPHS * H; i += 1024) {
    float v = sm[i];
    if (v != 0.f) atomicAdd(&pooled[i], v);
  }
}

__global__ __launch_bounds__(64) void out_kernel(
    const float* __restrict__ pooled, const float* __restrict__ w,
    const float* __restrict__ b, float* __restrict__ out) {
  int gph = blockIdx.x;
  int c = threadIdx.x;
  float v = pooled[gph * H + c] * w[c];
#pragma unroll
  for (int off = 32; off > 0; off >>= 1) v += __shfl_xor(v, off, 64);
  if (c == 0) out[gph] = v + b[0];
}

extern "C" void kernel_launch(void* const* d_in, const int* in_sizes, int n_in,
                              void* d_out, int out_size, void* d_ws, size_t ws_size,
                              hipStream_t stream) {
  const float* x       = (const float*)d_in[0];
  const int*   ei_edge = (const int*)d_in[1];
  const int*   ei_sub  = (const int*)d_in[2];
  const int*   ei_ns   = (const int*)d_in[3];
  const int*   ei_sn   = (const int*)d_in[4];
  const int*   batch   = (const int*)d_in[7];
  const float* emb_w   = (const float*)d_in[8];
  const float* emb_b   = (const float*)d_in[9];
  const float* conv_wl = (const float*)d_in[10];
  const float* conv_bl = (const float*)d_in[11];
  const float* conv_wr = (const float*)d_in[12];
  const float* ln_g    = (const float*)d_in[13];
  const float* ln_b    = (const float*)d_in[14];
  const float* out_w   = (const float*)d_in[15];
  const float* out_b   = (const float*)d_in[16];
  float* out = (float*)d_out;

  const size_t HB = (size_t)N_NODES * H * sizeof(float);   // 25.6 MB
  char* ws = (char*)d_ws;
  float* h      = (float*)(ws);                        // fp32, ground, j==3
  float* h0     = (float*)(ws + HB);                   // fp32 residual (ground)
  unsigned short* ab = (unsigned short*)(ws + 2 * HB); // [node][128] bf16 25.6MB
  // Persistent build outputs:
  int*   deg4   = (int*)(ws + 3 * HB);                           // 1.6 MB
  int*   S      = (int*)(ws + 78400000);                         // 1.6 MB
  int*   bcnt   = (int*)(ws + 92800000);
  int*   boff   = (int*)(ws + 92800512);
  int*   bcur   = (int*)(ws + 92801024);
  int*   blist  = (int*)(ws + 92801536);                         // 1.6 MB
  float* pooled = (float*)(ws + 94401536);                       // 32 KB
  unsigned short* wbt = (unsigned short*)(ws + 94434304);        // 1.38 MB
  int*   tdesc  = (int*)(ws + 95810560);                         // 25.6 KB
  int*   ntiles = (int*)(ws + 95836160);                         // 16 B
  unsigned short* ewbt = (unsigned short*)(ws + 95836608);       // 4 KB
  int*   bincur = (int*)(ws + 95841024);                         // 2 KB
  // Fixed-capacity bin regions (ws_size ~= 256 MiB, plenty of headroom):
  unsigned* binned = (unsigned*)(ws + 100000000);                // 16.8 MB
  int*   slots  = (int*)(ws + 117000000);                        // 16.8 MB

  const int* e0 = ei_edge, *e1 = ei_ns, *e2 = ei_sub, *e3 = ei_sn;

  // --- build ---
  wconv_kernel<<<(84 * 64 * 128 + H * F_IN + 255) / 256, 256, 0, stream>>>(
      conv_wl, conv_wr, emb_w, wbt, ewbt, bincur, bcnt);
  p3_binscatter<<<NBINS, 1024, 0, stream>>>(e0, e1, e2, e3, bincur, binned);
  p46_kernel<<<NBINS, 1024, 0, stream>>>(binned, bincur, deg4, S, slots, bcnt);
  bucket_scan<<<1, 128, 0, stream>>>(bcnt, boff, bcur, ntiles, tdesc);
  bucket_fill<<<dim3((N_NODES + 255) / 256, 4), 256, 0, stream>>>(deg4, bcur, blist);

  // --- network (self half ping-pongs 64 -> 0 -> 64 -> 0 -> h) ---
  emb_kernel<<<(N_NODES + 63) / 64, 256, 0, stream>>>(x, ewbt, emb_b, h0, ab, pooled);

  for (int j = 0; j < 4; ++j) {
    conv_kernel<<<MAX_TILES, 256, 0, stream>>>(
        h, ab, S + j * N_NODES, deg4 + j * N_NODES, slots,
        blist, tdesc, ntiles, wbt,
        conv_bl + (size_t)j * 21 * H, j,
        (j & 1) ? 0 : 64,          // inoff
        j < 3 ? 1 : 0, j == 3 ? 1 : 0);
  }

  ln_pool_kernel<<<POOL_BLOCKS, 1024, 0, stream>>>(h, h0, ln_g, ln_b, batch, pooled);
  out_kernel<<<NUM_GRAPHS, 64, 0, stream>>>(pooled, out_w, out_b, out);
}